// Round 1
// baseline (2176.901 us; speedup 1.0000x reference)
//
#include <hip/hip_runtime.h>

#define NN 100000
#define EE 1600000
#define DD 64
#define CC 10
#define GG 512
#define LL 5

// ---------------- scatter-add: agg[dst] += h[src], one thread per (edge, feat)
__global__ __launch_bounds__(256) void scatter_add_k(
    const float* __restrict__ h, const int* __restrict__ ei,
    float* __restrict__ agg)
{
    int tid = blockIdx.x * 256 + threadIdx.x;
    if (tid >= EE * DD) return;
    int f = tid & 63;
    int e = tid >> 6;                  // whole wave shares one edge
    int src = ei[e];
    int dst = ei[EE + e];
    atomicAdd(&agg[(size_t)dst * DD + f], h[(size_t)src * DD + f]);
}

// ---------------- fused GEMM (+input transform) + BN-stats partials
// MODE 0: in = (1+eps)*h + agg      (GIN combine, pre-MLP)
// MODE 1: in = relu(scale*z + shift) (BN1+ReLU applied on the fly)
// out: z = in @ W + b ; stats[0:64]=colsum, stats[64:128]=colsumsq
template<int MODE>
__global__ __launch_bounds__(256) void gemm_bn_k(
    const float* __restrict__ in0,
    const float* __restrict__ in1,   // agg (MODE 0) or scaleshift[128] (MODE 1)
    const float* __restrict__ epsArr, int l,
    const float* __restrict__ W, const float* __restrict__ bias,
    float* __restrict__ z, float* __restrict__ stats)
{
    __shared__ float4 inLDS4[1024];          // 64 rows x 64 cols
    __shared__ float red[512];
    float* inLDS = (float*)inLDS4;
    const int t = threadIdx.x;
    const int col = t & 63;
    const int q = t >> 6;                    // 0..3
    const int row0 = blockIdx.x * 64;
    float epsv = 0.0f;
    if (MODE == 0) epsv = 1.0f + epsArr[l];

    // stage 64 input rows into LDS (with transform)
    for (int i = t; i < 1024; i += 256) {
        int r = i >> 4;
        int c4 = i & 15;
        int gr = row0 + r;
        float4 v = make_float4(0.f, 0.f, 0.f, 0.f);
        if (gr < NN) {
            float4 a = ((const float4*)(in0 + (size_t)gr * DD))[c4];
            if (MODE == 0) {
                float4 b = ((const float4*)(in1 + (size_t)gr * DD))[c4];
                v.x = epsv * a.x + b.x;
                v.y = epsv * a.y + b.y;
                v.z = epsv * a.z + b.z;
                v.w = epsv * a.w + b.w;
            } else {
                float4 sc = ((const float4*)in1)[c4];
                float4 sh = ((const float4*)(in1 + DD))[c4];
                v.x = fmaxf(fmaf(sc.x, a.x, sh.x), 0.f);
                v.y = fmaxf(fmaf(sc.y, a.y, sh.y), 0.f);
                v.z = fmaxf(fmaf(sc.z, a.z, sh.z), 0.f);
                v.w = fmaxf(fmaf(sc.w, a.w, sh.w), 0.f);
            }
        }
        inLDS4[i] = v;
    }

    // W column in registers (coalesced loads: lanes = consecutive cols)
    float w[64];
    #pragma unroll
    for (int k = 0; k < 64; ++k) w[k] = W[k * DD + col];
    float bcol = bias[col];
    __syncthreads();

    float s = 0.f, ss = 0.f;
    for (int rr = 0; rr < 16; ++rr) {
        int rl = q + rr * 4;
        const float* row = inLDS + rl * DD;
        float acc = bcol;
        #pragma unroll
        for (int k = 0; k < 64; k += 4) {
            float4 a = *(const float4*)(row + k);   // wave-broadcast LDS read
            acc = fmaf(a.x, w[k],     acc);
            acc = fmaf(a.y, w[k + 1], acc);
            acc = fmaf(a.z, w[k + 2], acc);
            acc = fmaf(a.w, w[k + 3], acc);
        }
        int gr = row0 + rl;
        if (gr < NN) {
            z[(size_t)gr * DD + col] = acc;
            s += acc;
            ss = fmaf(acc, acc, ss);
        }
    }
    // per-block column partials -> global atomics (1563 adds/address, cheap)
    red[t] = s;
    red[256 + t] = ss;
    __syncthreads();
    if (t < 64) {
        float S  = red[t] + red[t + 64] + red[t + 128] + red[t + 192];
        float SS = red[256 + t] + red[256 + t + 64] + red[256 + t + 128] + red[256 + t + 192];
        atomicAdd(&stats[t], S);
        atomicAdd(&stats[DD + t], SS);
    }
}

// ---------------- BN finalize: scale/shift from sums
__global__ void bn_final_k(const float* __restrict__ stats,
                           const float* __restrict__ gamma, const float* __restrict__ beta,
                           int off, float* __restrict__ scaleshift)
{
    int f = threadIdx.x;   // 64 threads
    float inv_n = 1.0f / (float)NN;
    float mean = stats[f] * inv_n;
    float var  = stats[DD + f] * inv_n - mean * mean;
    float sc = gamma[off + f] * rsqrtf(var + 1e-5f);
    scaleshift[f] = sc;
    scaleshift[DD + f] = beta[off + f] - sc * mean;
}

// ---------------- outer BN apply + ReLU + graph pooling
__global__ __launch_bounds__(256) void apply_bn_pool_k(
    const float* __restrict__ z2, const float* __restrict__ scaleshift,
    const int* __restrict__ batch, float* __restrict__ hout,
    float* __restrict__ pooled)
{
    int tid = blockIdx.x * 256 + threadIdx.x;
    if (tid >= NN * DD) return;
    int f = tid & 63;
    int i = tid >> 6;
    float v = fmaxf(fmaf(scaleshift[f], z2[tid], scaleshift[DD + f]), 0.f);
    hout[tid] = v;
    atomicAdd(&pooled[(size_t)batch[i] * DD + f], v);
}

// ---------------- layer-0 pooling of raw x
__global__ __launch_bounds__(256) void pool0_k(
    const float* __restrict__ x, const int* __restrict__ batch,
    float* __restrict__ pooled)
{
    int tid = blockIdx.x * 256 + threadIdx.x;
    if (tid >= NN * DD) return;
    int f = tid & 63;
    int i = tid >> 6;
    atomicAdd(&pooled[(size_t)batch[i] * DD + f], x[tid]);
}

// ---------------- jumping-knowledge readout
__global__ void readout_k(const float* __restrict__ pooled,
                          const float* __restrict__ Wp, const float* __restrict__ bp,
                          float* __restrict__ out)
{
    int gc = blockIdx.x * blockDim.x + threadIdx.x;
    if (gc >= GG * CC) return;
    int g = gc / CC, c = gc - g * CC;
    float acc = 0.f;
    for (int l = 0; l < LL; ++l) {
        acc += bp[l * CC + c];
        const float* p  = pooled + ((size_t)l * GG + g) * DD;
        const float* wv = Wp + (size_t)l * DD * CC + c;
        #pragma unroll 8
        for (int f = 0; f < DD; ++f) acc = fmaf(p[f], wv[f * CC], acc);
    }
    out[gc] = acc;
}

extern "C" void kernel_launch(void* const* d_in, const int* in_sizes, int n_in,
                              void* d_out, int out_size, void* d_ws, size_t ws_size,
                              hipStream_t stream) {
    const float* x     = (const float*)d_in[0];
    const int*   ei    = (const int*)d_in[1];
    const int*   batch = (const int*)d_in[2];
    const float* eps   = (const float*)d_in[3];
    const float* W1    = (const float*)d_in[4];
    const float* b1    = (const float*)d_in[5];
    const float* g1    = (const float*)d_in[6];
    const float* be1   = (const float*)d_in[7];
    const float* W2    = (const float*)d_in[8];
    const float* b2    = (const float*)d_in[9];
    const float* gout  = (const float*)d_in[10];
    const float* beout = (const float*)d_in[11];
    const float* Wp    = (const float*)d_in[12];
    const float* bp    = (const float*)d_in[13];
    float* out = (float*)d_out;

    const size_t ND = (size_t)NN * DD;
    float* hcur   = (float*)d_ws;            // N x 64
    float* bufA   = hcur + ND;               // agg, then z2
    float* bufB   = bufA + ND;               // z1
    float* pooled = bufB + ND;               // 5 x G x 64
    float* stats  = pooled + (size_t)LL * GG * DD;  // 256 floats (bn1 | bn2)
    float* bnp    = stats + 256;             // 256 floats (scale/shift bn1 | bn2)

    hipMemcpyAsync(hcur, x, ND * sizeof(float), hipMemcpyDeviceToDevice, stream);
    hipMemsetAsync(pooled, 0, (size_t)LL * GG * DD * sizeof(float), stream);
    pool0_k<<<(NN * DD + 255) / 256, 256, 0, stream>>>(x, batch, pooled);

    for (int l = 0; l < LL - 1; ++l) {
        hipMemsetAsync(bufA, 0, ND * sizeof(float), stream);
        hipMemsetAsync(stats, 0, 256 * sizeof(float), stream);
        scatter_add_k<<<(EE * DD + 255) / 256, 256, 0, stream>>>(hcur, ei, bufA);
        gemm_bn_k<0><<<(NN + 63) / 64, 256, 0, stream>>>(
            hcur, bufA, eps, l, W1 + (size_t)l * DD * DD, b1 + l * DD, bufB, stats);
        bn_final_k<<<1, 64, 0, stream>>>(stats, g1, be1, l * DD, bnp);
        gemm_bn_k<1><<<(NN + 63) / 64, 256, 0, stream>>>(
            bufB, bnp, eps, 0, W2 + (size_t)l * DD * DD, b2 + l * DD, bufA, stats + 128);
        bn_final_k<<<1, 64, 0, stream>>>(stats + 128, gout, beout, l * DD, bnp + 128);
        apply_bn_pool_k<<<(NN * DD + 255) / 256, 256, 0, stream>>>(
            bufA, bnp + 128, batch, hcur, pooled + (size_t)(l + 1) * GG * DD);
    }
    readout_k<<<(GG * CC + 255) / 256, 256, 0, stream>>>(pooled, Wp, bp, out);
}

// Round 2
// 1179.050 us; speedup vs baseline: 1.8463x; 1.8463x over previous
//
#include <hip/hip_runtime.h>

#define NN 100000
#define EE 1600000
#define DD 64
#define CC 10
#define GG 512
#define LL 5
#define NPAD 100352            // NN padded to 256*392

// ================= CSR build =================
__global__ __launch_bounds__(256) void hist_k(const int* __restrict__ ei,
                                              int* __restrict__ deg) {
    int e = blockIdx.x * 256 + threadIdx.x;
    if (e < EE) atomicAdd(&deg[ei[EE + e]], 1);
}

// block-local exclusive scan (256 elems/block)
__global__ __launch_bounds__(256) void scan1_k(const int* __restrict__ deg,
                                               int* __restrict__ offs,
                                               int* __restrict__ bsums) {
    __shared__ int s[256];
    int t = threadIdx.x;
    int i = blockIdx.x * 256 + t;
    int v = deg[i];
    s[t] = v;
    __syncthreads();
    #pragma unroll
    for (int d = 1; d < 256; d <<= 1) {
        int a = (t >= d) ? s[t - d] : 0;
        __syncthreads();
        s[t] += a;
        __syncthreads();
    }
    offs[i] = s[t] - v;                 // exclusive, block-local
    if (t == 255) bsums[blockIdx.x] = s[255];
}

// single-block scan of block sums (392 <= 512)
__global__ __launch_bounds__(512) void scan2_k(int* __restrict__ bsums) {
    __shared__ int s[512];
    int t = threadIdx.x;
    int v = (t < NPAD / 256) ? bsums[t] : 0;
    s[t] = v;
    __syncthreads();
    #pragma unroll
    for (int d = 1; d < 512; d <<= 1) {
        int a = (t >= d) ? s[t - d] : 0;
        __syncthreads();
        s[t] += a;
        __syncthreads();
    }
    if (t < NPAD / 256) bsums[t] = s[t] - v;   // exclusive
}

__global__ __launch_bounds__(256) void scan3_k(int* __restrict__ offs,
                                               const int* __restrict__ bsums,
                                               int* __restrict__ pos) {
    int i = blockIdx.x * 256 + threadIdx.x;
    int o = offs[i] + bsums[blockIdx.x];
    offs[i] = o;
    pos[i] = o;
}

__global__ __launch_bounds__(256) void fill_k(const int* __restrict__ ei,
                                              int* __restrict__ pos,
                                              int* __restrict__ adj) {
    int e = blockIdx.x * 256 + threadIdx.x;
    if (e >= EE) return;
    int dst = ei[EE + e];
    int p = atomicAdd(&pos[dst], 1);
    adj[p] = ei[e];
}

// ================= gather + GIN combine =================
// quarter-wave (16 lanes) per node, float4 per lane: out[n] = (1+eps)*h[n] + sum_nbrs h[src]
__global__ __launch_bounds__(256) void gather_combine_k(
    const float* __restrict__ h, const int* __restrict__ adj,
    const int* __restrict__ offs, const float* __restrict__ epsArr, int l,
    float* __restrict__ out)
{
    int t = threadIdx.x;
    int c4 = t & 15;
    int n = blockIdx.x * 16 + (t >> 4);
    if (n >= NN) return;
    float epsv = 1.0f + epsArr[l];
    const float4* hrow = (const float4*)(h + (size_t)n * DD);
    float4 a = hrow[c4];
    float4 acc = make_float4(epsv * a.x, epsv * a.y, epsv * a.z, epsv * a.w);
    int j = offs[n], end = offs[n + 1];
    for (; j + 1 < end; j += 2) {
        int s0 = adj[j], s1 = adj[j + 1];
        float4 v0 = ((const float4*)(h + (size_t)s0 * DD))[c4];
        float4 v1 = ((const float4*)(h + (size_t)s1 * DD))[c4];
        acc.x += v0.x + v1.x; acc.y += v0.y + v1.y;
        acc.z += v0.z + v1.z; acc.w += v0.w + v1.w;
    }
    if (j < end) {
        float4 v0 = ((const float4*)(h + (size_t)adj[j] * DD))[c4];
        acc.x += v0.x; acc.y += v0.y; acc.z += v0.z; acc.w += v0.w;
    }
    ((float4*)(out + (size_t)n * DD))[c4] = acc;
}

// ================= fused GEMM + BN-stats partials =================
// MODE 0: in = in0 (identity)
// MODE 1: in = relu(scale*in0 + shift)  (BN1+ReLU on the fly)
template<int MODE>
__global__ __launch_bounds__(256) void gemm_bn_k(
    const float* __restrict__ in0,
    const float* __restrict__ ss,    // scaleshift[128] (MODE 1 only)
    const float* __restrict__ W, const float* __restrict__ bias,
    float* __restrict__ z, float* __restrict__ stats)
{
    __shared__ float4 inLDS4[1024];          // 64 rows x 64 cols
    __shared__ float red[512];
    float* inLDS = (float*)inLDS4;
    const int t = threadIdx.x;
    const int col = t & 63;
    const int q = t >> 6;                    // 0..3
    const int row0 = blockIdx.x * 64;

    for (int i = t; i < 1024; i += 256) {
        int r = i >> 4;
        int c4 = i & 15;
        int gr = row0 + r;
        float4 v = make_float4(0.f, 0.f, 0.f, 0.f);
        if (gr < NN) {
            float4 a = ((const float4*)(in0 + (size_t)gr * DD))[c4];
            if (MODE == 0) {
                v = a;
            } else {
                float4 sc = ((const float4*)ss)[c4];
                float4 sh = ((const float4*)(ss + DD))[c4];
                v.x = fmaxf(fmaf(sc.x, a.x, sh.x), 0.f);
                v.y = fmaxf(fmaf(sc.y, a.y, sh.y), 0.f);
                v.z = fmaxf(fmaf(sc.z, a.z, sh.z), 0.f);
                v.w = fmaxf(fmaf(sc.w, a.w, sh.w), 0.f);
            }
        }
        inLDS4[i] = v;
    }

    float w[64];
    #pragma unroll
    for (int k = 0; k < 64; ++k) w[k] = W[k * DD + col];
    float bcol = bias[col];
    __syncthreads();

    float s = 0.f, ssq = 0.f;
    for (int rr = 0; rr < 16; ++rr) {
        int rl = q + rr * 4;
        const float* row = inLDS + rl * DD;
        float acc = bcol;
        #pragma unroll
        for (int k = 0; k < 64; k += 4) {
            float4 a = *(const float4*)(row + k);
            acc = fmaf(a.x, w[k],     acc);
            acc = fmaf(a.y, w[k + 1], acc);
            acc = fmaf(a.z, w[k + 2], acc);
            acc = fmaf(a.w, w[k + 3], acc);
        }
        int gr = row0 + rl;
        if (gr < NN) {
            z[(size_t)gr * DD + col] = acc;
            s += acc;
            ssq = fmaf(acc, acc, ssq);
        }
    }
    red[t] = s;
    red[256 + t] = ssq;
    __syncthreads();
    if (t < 64) {
        float S  = red[t] + red[t + 64] + red[t + 128] + red[t + 192];
        float SS = red[256 + t] + red[256 + t + 64] + red[256 + t + 128] + red[256 + t + 192];
        atomicAdd(&stats[t], S);
        atomicAdd(&stats[DD + t], SS);
    }
}

// ================= BN finalize =================
__global__ void bn_final_k(const float* __restrict__ stats,
                           const float* __restrict__ gamma, const float* __restrict__ beta,
                           int off, float* __restrict__ scaleshift)
{
    int f = threadIdx.x;   // 64 threads
    float inv_n = 1.0f / (float)NN;
    float mean = stats[f] * inv_n;
    float var  = stats[DD + f] * inv_n - mean * mean;
    float sc = gamma[off + f] * rsqrtf(var + 1e-5f);
    scaleshift[f] = sc;
    scaleshift[DD + f] = beta[off + f] - sc * mean;
}

// ================= outer BN apply + ReLU + pool =================
__global__ __launch_bounds__(256) void apply_bn_pool_k(
    const float* __restrict__ z2, const float* __restrict__ scaleshift,
    const int* __restrict__ batch, float* __restrict__ hout,
    float* __restrict__ pooled)
{
    int tid = blockIdx.x * 256 + threadIdx.x;
    if (tid >= NN * DD) return;
    int f = tid & 63;
    int i = tid >> 6;
    float v = fmaxf(fmaf(scaleshift[f], z2[tid], scaleshift[DD + f]), 0.f);
    hout[tid] = v;
    atomicAdd(&pooled[(size_t)batch[i] * DD + f], v);
}

__global__ __launch_bounds__(256) void pool0_k(
    const float* __restrict__ x, const int* __restrict__ batch,
    float* __restrict__ pooled)
{
    int tid = blockIdx.x * 256 + threadIdx.x;
    if (tid >= NN * DD) return;
    int f = tid & 63;
    int i = tid >> 6;
    atomicAdd(&pooled[(size_t)batch[i] * DD + f], x[tid]);
}

// ================= jumping-knowledge readout =================
__global__ void readout_k(const float* __restrict__ pooled,
                          const float* __restrict__ Wp, const float* __restrict__ bp,
                          float* __restrict__ out)
{
    int gc = blockIdx.x * blockDim.x + threadIdx.x;
    if (gc >= GG * CC) return;
    int g = gc / CC, c = gc - g * CC;
    float acc = 0.f;
    for (int l = 0; l < LL; ++l) {
        acc += bp[l * CC + c];
        const float* p  = pooled + ((size_t)l * GG + g) * DD;
        const float* wv = Wp + (size_t)l * DD * CC + c;
        #pragma unroll 8
        for (int f = 0; f < DD; ++f) acc = fmaf(p[f], wv[f * CC], acc);
    }
    out[gc] = acc;
}

extern "C" void kernel_launch(void* const* d_in, const int* in_sizes, int n_in,
                              void* d_out, int out_size, void* d_ws, size_t ws_size,
                              hipStream_t stream) {
    const float* x     = (const float*)d_in[0];
    const int*   ei    = (const int*)d_in[1];
    const int*   batch = (const int*)d_in[2];
    const float* eps   = (const float*)d_in[3];
    const float* W1    = (const float*)d_in[4];
    const float* b1    = (const float*)d_in[5];
    const float* g1    = (const float*)d_in[6];
    const float* be1   = (const float*)d_in[7];
    const float* W2    = (const float*)d_in[8];
    const float* b2    = (const float*)d_in[9];
    const float* gout  = (const float*)d_in[10];
    const float* beout = (const float*)d_in[11];
    const float* Wp    = (const float*)d_in[12];
    const float* bp    = (const float*)d_in[13];
    float* out = (float*)d_out;

    const size_t ND = (size_t)NN * DD;
    float* hcur   = (float*)d_ws;                   // N x 64
    float* bufA   = hcur + ND;                      // combined / z2
    float* bufB   = bufA + ND;                      // z1
    float* pooled = bufB + ND;                      // 5 x G x 64
    float* stats  = pooled + (size_t)LL * GG * DD;  // 256 floats
    float* bnp    = stats + 256;                    // 256 floats
    int*   deg    = (int*)(bnp + 256);              // NPAD
    int*   offs   = deg + NPAD + 256;               // NPAD (+1 readable)
    int*   pos    = offs + NPAD + 256;              // NPAD
    int*   bsums  = pos + NPAD;                     // 512
    int*   adj    = bsums + 512;                    // EE

    // ---- CSR build (once per call) ----
    hipMemsetAsync(deg, 0, NPAD * sizeof(int), stream);
    hist_k<<<(EE + 255) / 256, 256, 0, stream>>>(ei, deg);
    scan1_k<<<NPAD / 256, 256, 0, stream>>>(deg, offs, bsums);
    scan2_k<<<1, 512, 0, stream>>>(bsums);
    scan3_k<<<NPAD / 256, 256, 0, stream>>>(offs, bsums, pos);
    fill_k<<<(EE + 255) / 256, 256, 0, stream>>>(ei, pos, adj);

    hipMemsetAsync(pooled, 0, (size_t)LL * GG * DD * sizeof(float), stream);
    pool0_k<<<(NN * DD + 255) / 256, 256, 0, stream>>>(x, batch, pooled);

    for (int l = 0; l < LL - 1; ++l) {
        const float* hin = (l == 0) ? x : hcur;
        hipMemsetAsync(stats, 0, 256 * sizeof(float), stream);
        gather_combine_k<<<(NN + 15) / 16, 256, 0, stream>>>(hin, adj, offs, eps, l, bufA);
        gemm_bn_k<0><<<(NN + 63) / 64, 256, 0, stream>>>(
            bufA, bnp, W1 + (size_t)l * DD * DD, b1 + l * DD, bufB, stats);
        bn_final_k<<<1, 64, 0, stream>>>(stats, g1, be1, l * DD, bnp);
        gemm_bn_k<1><<<(NN + 63) / 64, 256, 0, stream>>>(
            bufB, bnp, W2 + (size_t)l * DD * DD, b2 + l * DD, bufA, stats + 128);
        bn_final_k<<<1, 64, 0, stream>>>(stats + 128, gout, beout, l * DD, bnp + 128);
        apply_bn_pool_k<<<(NN * DD + 255) / 256, 256, 0, stream>>>(
            bufA, bnp + 128, batch, hcur, pooled + (size_t)(l + 1) * GG * DD);
    }
    readout_k<<<(GG * CC + 255) / 256, 256, 0, stream>>>(pooled, Wp, bp, out);
}